// Round 5
// baseline (3460.807 us; speedup 1.0000x reference)
//
#include <hip/hip_runtime.h>
#include <hip/hip_bf16.h>

#define T_TOK 8192
#define D_DIM 1024
#define E_NUM 16
#define I_DIM 2048
#define K_TOP 4
#define NPAIR (T_TOK * K_TOP)

typedef float f32x4 __attribute__((ext_vector_type(4)));
typedef __bf16 bf16x8 __attribute__((ext_vector_type(8)));
typedef unsigned short ushort8_t __attribute__((ext_vector_type(8)));

// ---------------- workspace layout (bytes) ----------------
#define WS_X    0ull
#define WS_W13  (WS_X    + (size_t)T_TOK * D_DIM * 2)             // x bf16: 16 MiB
#define WS_W2   (WS_W13  + (size_t)E_NUM * 2 * I_DIM * D_DIM * 2) // w13 bf16: 128 MiB
#define WS_H    (WS_W2   + (size_t)E_NUM * D_DIM * I_DIM * 2)     // w2 bf16: 64 MiB
#define WS_TKID (WS_H    + (size_t)NPAIR * I_DIM * 2)             // h bf16: 128 MiB
#define WS_TKW  (WS_TKID + (size_t)T_TOK * K_TOP * 4)
#define WS_PTOK (WS_TKW  + (size_t)T_TOK * K_TOP * 4)
#define WS_PW   (WS_PTOK + (size_t)NPAIR * 4)
#define WS_META (WS_PW   + (size_t)NPAIR * 4)
// META ints: cnt[16], cur[16], off[16]
#define WS_PAIR (WS_META + 256)                                   // pair_of[t*4+k] -> pos
#define WS_PART (WS_PAIR + (size_t)NPAIR * 4)                     // fp32 partial [NPAIR][D]
#define WS_NEED_FULL (WS_PART + (size_t)NPAIR * D_DIM * 4)

__device__ inline unsigned short f2bf(float f) {
    unsigned u = __builtin_bit_cast(unsigned, f);
    u += 0x7fffu + ((u >> 16) & 1u);   // round-to-nearest-even
    return (unsigned short)(u >> 16);
}

// ---------------- fp32 -> bf16 conversion ----------------
__global__ void cvt_kernel(const float* __restrict__ in,
                           unsigned short* __restrict__ out, int n) {
    int idx = blockIdx.x * blockDim.x + threadIdx.x;
    int stride = gridDim.x * blockDim.x;
    for (int i = idx * 4; i < n; i += stride * 4) {
        float4 v = *(const float4*)(in + i);
        ushort4 o;
        o.x = f2bf(v.x); o.y = f2bf(v.y); o.z = f2bf(v.z); o.w = f2bf(v.w);
        *(ushort4*)(out + i) = o;
    }
}

// ---------------- router: top-4 softmax ----------------
__global__ void router_kernel(const float* __restrict__ logits,
                              int* __restrict__ tk_id, float* __restrict__ tk_w,
                              int* __restrict__ cnt) {
    int t = blockIdx.x * blockDim.x + threadIdx.x;
    if (t >= T_TOK) return;
    float l[E_NUM];
    const float4* lp = (const float4*)(logits + (size_t)t * E_NUM);
#pragma unroll
    for (int i = 0; i < 4; i++) {
        float4 v = lp[i];
        l[4 * i] = v.x; l[4 * i + 1] = v.y; l[4 * i + 2] = v.z; l[4 * i + 3] = v.w;
    }
    unsigned used = 0;
    int ids[K_TOP]; float vs[K_TOP];
#pragma unroll
    for (int k = 0; k < K_TOP; k++) {
        float best = -1e30f; int bi = 0;
#pragma unroll
        for (int e = 0; e < E_NUM; e++) {
            bool ok = !((used >> e) & 1u);
            if (ok && l[e] > best) { best = l[e]; bi = e; }
        }
        ids[k] = bi; vs[k] = best; used |= (1u << bi);
    }
    float m = vs[0];
    float s = 0.f;
#pragma unroll
    for (int k = 0; k < K_TOP; k++) { vs[k] = expf(vs[k] - m); s += vs[k]; }
    float inv = 1.f / s;
#pragma unroll
    for (int k = 0; k < K_TOP; k++) {
        tk_id[t * K_TOP + k] = ids[k];
        tk_w[t * K_TOP + k] = vs[k] * inv;
        atomicAdd(&cnt[ids[k]], 1);
    }
}

// ---------------- offsets: exclusive prefix over 16 counts ----------------
__global__ void offsets_kernel(const int* __restrict__ cnt,
                               int* __restrict__ off, int* __restrict__ cur) {
    if (threadIdx.x == 0 && blockIdx.x == 0) {
        int o = 0;
        for (int e = 0; e < E_NUM; e++) { off[e] = o; cur[e] = o; o += cnt[e]; }
    }
}

// ---------------- scatter tokens into expert buckets ----------------
__global__ void scatter_kernel(const int* __restrict__ tk_id,
                               const float* __restrict__ tk_w,
                               int* __restrict__ cur,
                               int* __restrict__ p_tok, float* __restrict__ p_w,
                               int* __restrict__ pair_of) {
    int t = blockIdx.x * blockDim.x + threadIdx.x;
    if (t >= T_TOK) return;
#pragma unroll
    for (int k = 0; k < K_TOP; k++) {
        int e = tk_id[t * K_TOP + k];
        int pos = atomicAdd(&cur[e], 1);
        p_tok[pos] = t;
        p_w[pos] = tk_w[t * K_TOP + k];
        pair_of[t * K_TOP + k] = pos;
    }
}

// ---------------- GEMM1: h = silu(x*w13g^T) * (x*w13u^T), gathered rows ----------------
__global__ __launch_bounds__(256, 4) void gemm1_kernel(
    const unsigned short* __restrict__ xb, const unsigned short* __restrict__ w13,
    const int* __restrict__ cnt, const int* __restrict__ off,
    const int* __restrict__ p_tok, unsigned short* __restrict__ h) {
    int e = blockIdx.z;
    int cnt_e = cnt[e];
    int m0 = blockIdx.y * 128;
    if (m0 >= cnt_e) return;
    int n0 = blockIdx.x * 128;
    int base = off[e];

    __shared__ unsigned short As[128][40];
    __shared__ unsigned short Bg[128][40];
    __shared__ unsigned short Bu[128][40];
    __shared__ int toks[128];

    int tid = threadIdx.x;
    int lane = tid & 63, wid = tid >> 6;
    int wm = wid >> 1, wn = wid & 1;

    if (tid < 128) {
        int r = m0 + tid;
        toks[tid] = (r < cnt_e) ? p_tok[base + r] : -1;
    }
    __syncthreads();

    int sr = tid >> 1;          // staged row 0..127
    int sc = (tid & 1) * 16;    // staged col 0 or 16
    int atok = toks[sr];
    const unsigned short* w13e = w13 + (size_t)e * (2 * I_DIM) * D_DIM;
    const unsigned short* gRow = w13e + (size_t)(n0 + sr) * D_DIM;
    const unsigned short* uRow = w13e + (size_t)(I_DIM + n0 + sr) * D_DIM;
    const unsigned short* aRow = (atok >= 0) ? (xb + (size_t)atok * D_DIM) : (const unsigned short*)0;

    f32x4 accg[4][4], accu[4][4];
#pragma unroll
    for (int m = 0; m < 4; m++)
#pragma unroll
        for (int n = 0; n < 4; n++) {
            accg[m][n] = (f32x4){0.f, 0.f, 0.f, 0.f};
            accu[m][n] = (f32x4){0.f, 0.f, 0.f, 0.f};
        }

    for (int k0 = 0; k0 < D_DIM; k0 += 32) {
        ushort8_t av0 = {0,0,0,0,0,0,0,0}, av1 = {0,0,0,0,0,0,0,0};
        if (aRow) {
            av0 = *(const ushort8_t*)(aRow + k0 + sc);
            av1 = *(const ushort8_t*)(aRow + k0 + sc + 8);
        }
        ushort8_t g0 = *(const ushort8_t*)(gRow + k0 + sc);
        ushort8_t g1 = *(const ushort8_t*)(gRow + k0 + sc + 8);
        ushort8_t u0 = *(const ushort8_t*)(uRow + k0 + sc);
        ushort8_t u1 = *(const ushort8_t*)(uRow + k0 + sc + 8);
        *(ushort8_t*)&As[sr][sc]     = av0;
        *(ushort8_t*)&As[sr][sc + 8] = av1;
        *(ushort8_t*)&Bg[sr][sc]     = g0;
        *(ushort8_t*)&Bg[sr][sc + 8] = g1;
        *(ushort8_t*)&Bu[sr][sc]     = u0;
        *(ushort8_t*)&Bu[sr][sc + 8] = u1;
        __syncthreads();

        int fr = lane & 15, fk = (lane >> 4) * 8;
        bf16x8 a[4], bg[4], bu[4];
#pragma unroll
        for (int m = 0; m < 4; m++) a[m] = *(const bf16x8*)&As[wm * 64 + m * 16 + fr][fk];
#pragma unroll
        for (int n = 0; n < 4; n++) {
            bg[n] = *(const bf16x8*)&Bg[wn * 64 + n * 16 + fr][fk];
            bu[n] = *(const bf16x8*)&Bu[wn * 64 + n * 16 + fr][fk];
        }
#pragma unroll
        for (int m = 0; m < 4; m++)
#pragma unroll
            for (int n = 0; n < 4; n++) {
                accg[m][n] = __builtin_amdgcn_mfma_f32_16x16x32_bf16(a[m], bg[n], accg[m][n], 0, 0, 0);
                accu[m][n] = __builtin_amdgcn_mfma_f32_16x16x32_bf16(a[m], bu[n], accu[m][n], 0, 0, 0);
            }
        __syncthreads();
    }

    // epilogue: h = silu(g)*u, bf16
    int fr = lane & 15, fq = lane >> 4;
#pragma unroll
    for (int m = 0; m < 4; m++) {
#pragma unroll
        for (int j = 0; j < 4; j++) {
            int rr = wm * 64 + m * 16 + fq * 4 + j;
            if (m0 + rr < cnt_e) {
                size_t hrow = (size_t)(base + m0 + rr) * I_DIM;
#pragma unroll
                for (int n = 0; n < 4; n++) {
                    float g = accg[m][n][j];
                    float u = accu[m][n][j];
                    float hh = (g / (1.f + __expf(-g))) * u;
                    h[hrow + n0 + wn * 64 + n * 16 + fr] = f2bf(hh);
                }
            }
        }
    }
}

// ---------------- GEMM2: partial[pos] = pw * (h[pos] @ w2^T)  (or atomic fallback) ----------------
template<bool USE_ATOMIC>
__global__ __launch_bounds__(256, 4) void gemm2_kernel(
    const unsigned short* __restrict__ h, const unsigned short* __restrict__ w2,
    const int* __restrict__ cnt, const int* __restrict__ off,
    const int* __restrict__ p_tok, const float* __restrict__ p_w,
    float* __restrict__ dst) {
    int e = blockIdx.z;
    int cnt_e = cnt[e];
    int m0 = blockIdx.y * 128;
    if (m0 >= cnt_e) return;
    int n0 = blockIdx.x * 128;
    int base = off[e];

    __shared__ unsigned short As[128][40];
    __shared__ unsigned short Bs[128][40];
    __shared__ int toks[128];
    __shared__ float pws[128];

    int tid = threadIdx.x;
    int lane = tid & 63, wid = tid >> 6;
    int wm = wid >> 1, wn = wid & 1;

    if (tid < 128) {
        int r = m0 + tid;
        toks[tid] = (r < cnt_e) ? p_tok[base + r] : 0;
        pws[tid]  = (r < cnt_e) ? p_w[base + r] : 0.f;
    }
    __syncthreads();

    int sr = tid >> 1;
    int sc = (tid & 1) * 16;
    bool arow_ok = (m0 + sr) < cnt_e;
    const unsigned short* aRow = h + (size_t)(base + m0 + sr) * I_DIM;
    const unsigned short* bRow = w2 + (size_t)e * D_DIM * I_DIM + (size_t)(n0 + sr) * I_DIM;

    f32x4 acc[4][4];
#pragma unroll
    for (int m = 0; m < 4; m++)
#pragma unroll
        for (int n = 0; n < 4; n++) acc[m][n] = (f32x4){0.f, 0.f, 0.f, 0.f};

    for (int k0 = 0; k0 < I_DIM; k0 += 32) {
        ushort8_t a0 = {0,0,0,0,0,0,0,0}, a1 = {0,0,0,0,0,0,0,0};
        if (arow_ok) {
            a0 = *(const ushort8_t*)(aRow + k0 + sc);
            a1 = *(const ushort8_t*)(aRow + k0 + sc + 8);
        }
        ushort8_t b0 = *(const ushort8_t*)(bRow + k0 + sc);
        ushort8_t b1 = *(const ushort8_t*)(bRow + k0 + sc + 8);
        *(ushort8_t*)&As[sr][sc]     = a0;
        *(ushort8_t*)&As[sr][sc + 8] = a1;
        *(ushort8_t*)&Bs[sr][sc]     = b0;
        *(ushort8_t*)&Bs[sr][sc + 8] = b1;
        __syncthreads();

        int fr = lane & 15, fk = (lane >> 4) * 8;
        bf16x8 a[4], b[4];
#pragma unroll
        for (int m = 0; m < 4; m++) a[m] = *(const bf16x8*)&As[wm * 64 + m * 16 + fr][fk];
#pragma unroll
        for (int n = 0; n < 4; n++) b[n] = *(const bf16x8*)&Bs[wn * 64 + n * 16 + fr][fk];
#pragma unroll
        for (int m = 0; m < 4; m++)
#pragma unroll
            for (int n = 0; n < 4; n++)
                acc[m][n] = __builtin_amdgcn_mfma_f32_16x16x32_bf16(a[m], b[n], acc[m][n], 0, 0, 0);
        __syncthreads();
    }

    int fr = lane & 15, fq = lane >> 4;
#pragma unroll
    for (int m = 0; m < 4; m++) {
#pragma unroll
        for (int j = 0; j < 4; j++) {
            int rr = wm * 64 + m * 16 + fq * 4 + j;
            if (m0 + rr < cnt_e) {
                float w = pws[rr];
#pragma unroll
                for (int n = 0; n < 4; n++) {
                    int col = n0 + wn * 64 + n * 16 + fr;
                    float v = acc[m][n][j] * w;
                    if (USE_ATOMIC) {
                        atomicAdd(&dst[(size_t)toks[rr] * D_DIM + col], v);
                    } else {
                        dst[(size_t)(base + m0 + rr) * D_DIM + col] = v;
                    }
                }
            }
        }
    }
}

// ---------------- combine: out[t] = sum_k partial[pair_of[t,k]] ----------------
__global__ __launch_bounds__(256) void combine_kernel(
    const float* __restrict__ part, const int* __restrict__ pair_of,
    float* __restrict__ out) {
    int t = blockIdx.x;
    int c = threadIdx.x * 4;
    int4 pr = *(const int4*)(pair_of + t * K_TOP);
    float4 s0 = *(const float4*)(part + (size_t)pr.x * D_DIM + c);
    float4 s1 = *(const float4*)(part + (size_t)pr.y * D_DIM + c);
    float4 s2 = *(const float4*)(part + (size_t)pr.z * D_DIM + c);
    float4 s3 = *(const float4*)(part + (size_t)pr.w * D_DIM + c);
    float4 r;
    r.x = (s0.x + s1.x) + (s2.x + s3.x);
    r.y = (s0.y + s1.y) + (s2.y + s3.y);
    r.z = (s0.z + s1.z) + (s2.z + s3.z);
    r.w = (s0.w + s1.w) + (s2.w + s3.w);
    *(float4*)(out + (size_t)t * D_DIM + c) = r;
}

// ---------------- launch ----------------
extern "C" void kernel_launch(void* const* d_in, const int* in_sizes, int n_in,
                              void* d_out, int out_size, void* d_ws, size_t ws_size,
                              hipStream_t stream) {
    const float* x      = (const float*)d_in[0];
    const float* logits = (const float*)d_in[1];
    const float* w13    = (const float*)d_in[2];
    const float* w2     = (const float*)d_in[3];
    float* out = (float*)d_out;
    char* ws = (char*)d_ws;

    unsigned short* xb   = (unsigned short*)(ws + WS_X);
    unsigned short* w13b = (unsigned short*)(ws + WS_W13);
    unsigned short* w2b  = (unsigned short*)(ws + WS_W2);
    unsigned short* hbuf = (unsigned short*)(ws + WS_H);
    int*   tk_id = (int*)(ws + WS_TKID);
    float* tk_w  = (float*)(ws + WS_TKW);
    int*   p_tok = (int*)(ws + WS_PTOK);
    float* p_w   = (float*)(ws + WS_PW);
    int* meta = (int*)(ws + WS_META);
    int* cnt = meta;
    int* cur = meta + 16;
    int* off = meta + 32;
    int*   pair_of = (int*)(ws + WS_PAIR);
    float* part    = (float*)(ws + WS_PART);

    bool full = (ws_size >= WS_NEED_FULL);

    hipMemsetAsync(meta, 0, 32 * sizeof(int), stream);
    if (!full) hipMemsetAsync(out, 0, (size_t)T_TOK * D_DIM * sizeof(float), stream);

    cvt_kernel<<<1024, 256, 0, stream>>>(x, xb, T_TOK * D_DIM);
    cvt_kernel<<<2048, 256, 0, stream>>>(w13, w13b, E_NUM * 2 * I_DIM * D_DIM);
    cvt_kernel<<<2048, 256, 0, stream>>>(w2, w2b, E_NUM * D_DIM * I_DIM);

    router_kernel<<<T_TOK / 256, 256, 0, stream>>>(logits, tk_id, tk_w, cnt);
    offsets_kernel<<<1, 64, 0, stream>>>(cnt, off, cur);
    scatter_kernel<<<T_TOK / 256, 256, 0, stream>>>(tk_id, tk_w, cur, p_tok, p_w, pair_of);

    dim3 g1(I_DIM / 128, 64, E_NUM);
    gemm1_kernel<<<g1, 256, 0, stream>>>(xb, w13b, cnt, off, p_tok, hbuf);

    dim3 g2(D_DIM / 128, 64, E_NUM);
    if (full) {
        gemm2_kernel<false><<<g2, 256, 0, stream>>>(hbuf, w2b, cnt, off, p_tok, p_w, part);
        combine_kernel<<<T_TOK, 256, 0, stream>>>(part, pair_of, out);
    } else {
        gemm2_kernel<true><<<g2, 256, 0, stream>>>(hbuf, w2b, cnt, off, p_tok, p_w, out);
    }
}

// Round 10
// 1273.833 us; speedup vs baseline: 2.7168x; 2.7168x over previous
//
#include <hip/hip_runtime.h>
#include <hip/hip_bf16.h>

#define T_TOK 8192
#define D_DIM 1024
#define E_NUM 16
#define I_DIM 2048
#define K_TOP 4
#define NPAIR (T_TOK * K_TOP)

typedef float f32x4 __attribute__((ext_vector_type(4)));
typedef __bf16 bf16x8 __attribute__((ext_vector_type(8)));
typedef unsigned int u32;

// ---------------- workspace layout (bytes) ----------------
#define WS_X    0ull
#define WS_W13  (WS_X    + (size_t)T_TOK * D_DIM * 2)             // x bf16: 16 MiB
#define WS_W2   (WS_W13  + (size_t)E_NUM * 2 * I_DIM * D_DIM * 2) // w13 bf16: 128 MiB
#define WS_H    (WS_W2   + (size_t)E_NUM * D_DIM * I_DIM * 2)     // w2 bf16: 64 MiB
#define WS_TKID (WS_H    + (size_t)NPAIR * I_DIM * 2)             // h bf16: 128 MiB
#define WS_TKW  (WS_TKID + (size_t)T_TOK * K_TOP * 4)
#define WS_PTOK (WS_TKW  + (size_t)T_TOK * K_TOP * 4)
#define WS_PW   (WS_PTOK + (size_t)NPAIR * 4)
#define WS_META (WS_PW   + (size_t)NPAIR * 4)
// META ints: cnt[16], cur[16], off[16]
#define WS_PAIR (WS_META + 256)                                   // pair_of[t*4+k] -> pos
#define WS_PART (WS_PAIR + (size_t)NPAIR * 4)                     // fp32 partial [NPAIR][D]
#define WS_NEED_FULL (WS_PART + (size_t)NPAIR * D_DIM * 4)

__device__ inline unsigned short f2bf(float f) {
    unsigned u = __builtin_bit_cast(unsigned, f);
    u += 0x7fffu + ((u >> 16) & 1u);   // round-to-nearest-even
    return (unsigned short)(u >> 16);
}

// async global->LDS, 16B per lane; LDS dest = wave-uniform base + lane*16
__device__ inline void gll16(const unsigned short* g, unsigned short* l) {
    __builtin_amdgcn_global_load_lds(
        (const __attribute__((address_space(1))) u32*)g,
        (__attribute__((address_space(3))) u32*)l, 16, 0, 0);
}

// ---------------- fp32 -> bf16 conversion ----------------
__global__ void cvt_kernel(const float* __restrict__ in,
                           unsigned short* __restrict__ out, int n) {
    int idx = blockIdx.x * blockDim.x + threadIdx.x;
    int stride = gridDim.x * blockDim.x;
    for (int i = idx * 4; i < n; i += stride * 4) {
        float4 v = *(const float4*)(in + i);
        ushort4 o;
        o.x = f2bf(v.x); o.y = f2bf(v.y); o.z = f2bf(v.z); o.w = f2bf(v.w);
        *(ushort4*)(out + i) = o;
    }
}

// ---------------- router: top-4 softmax ----------------
__global__ void router_kernel(const float* __restrict__ logits,
                              int* __restrict__ tk_id, float* __restrict__ tk_w,
                              int* __restrict__ cnt) {
    int t = blockIdx.x * blockDim.x + threadIdx.x;
    if (t >= T_TOK) return;
    float l[E_NUM];
    const float4* lp = (const float4*)(logits + (size_t)t * E_NUM);
#pragma unroll
    for (int i = 0; i < 4; i++) {
        float4 v = lp[i];
        l[4 * i] = v.x; l[4 * i + 1] = v.y; l[4 * i + 2] = v.z; l[4 * i + 3] = v.w;
    }
    unsigned used = 0;
    int ids[K_TOP]; float vs[K_TOP];
#pragma unroll
    for (int k = 0; k < K_TOP; k++) {
        float best = -1e30f; int bi = 0;
#pragma unroll
        for (int e = 0; e < E_NUM; e++) {
            bool ok = !((used >> e) & 1u);
            if (ok && l[e] > best) { best = l[e]; bi = e; }
        }
        ids[k] = bi; vs[k] = best; used |= (1u << bi);
    }
    float m = vs[0];
    float s = 0.f;
#pragma unroll
    for (int k = 0; k < K_TOP; k++) { vs[k] = expf(vs[k] - m); s += vs[k]; }
    float inv = 1.f / s;
#pragma unroll
    for (int k = 0; k < K_TOP; k++) {
        tk_id[t * K_TOP + k] = ids[k];
        tk_w[t * K_TOP + k] = vs[k] * inv;
        atomicAdd(&cnt[ids[k]], 1);
    }
}

// ---------------- offsets: exclusive prefix over 16 counts ----------------
__global__ void offsets_kernel(const int* __restrict__ cnt,
                               int* __restrict__ off, int* __restrict__ cur) {
    if (threadIdx.x == 0 && blockIdx.x == 0) {
        int o = 0;
        for (int e = 0; e < E_NUM; e++) { off[e] = o; cur[e] = o; o += cnt[e]; }
    }
}

// ---------------- scatter tokens into expert buckets ----------------
__global__ void scatter_kernel(const int* __restrict__ tk_id,
                               const float* __restrict__ tk_w,
                               int* __restrict__ cur,
                               int* __restrict__ p_tok, float* __restrict__ p_w,
                               int* __restrict__ pair_of) {
    int t = blockIdx.x * blockDim.x + threadIdx.x;
    if (t >= T_TOK) return;
#pragma unroll
    for (int k = 0; k < K_TOP; k++) {
        int e = tk_id[t * K_TOP + k];
        int pos = atomicAdd(&cur[e], 1);
        p_tok[pos] = t;
        p_w[pos] = tk_w[t * K_TOP + k];
        pair_of[t * K_TOP + k] = pos;
    }
}

// ---------------- GEMM1: h = silu(x*w13g^T) * (x*w13u^T), gathered rows ----------
// 128x128 tile, BK=32, global_load_lds width-16 staging (m97 structure),
// linear LDS [128][32]. launch_bounds(256,2): dual accumulator needs ~220 regs.
__global__ __launch_bounds__(256, 2) void gemm1_kernel(
    const unsigned short* __restrict__ xb, const unsigned short* __restrict__ w13,
    const int* __restrict__ cnt, const int* __restrict__ off,
    const int* __restrict__ p_tok, unsigned short* __restrict__ h) {
    int e = blockIdx.z;
    int cnt_e = cnt[e];
    int m0 = blockIdx.y * 128;
    if (m0 >= cnt_e) return;
    int n0 = blockIdx.x * 128;
    int base = off[e];

    __shared__ unsigned short As[128 * 32];
    __shared__ unsigned short Bg[128 * 32];
    __shared__ unsigned short Bu[128 * 32];
    __shared__ int toks[128];

    int tid = threadIdx.x;
    int lane = tid & 63, wid = tid >> 6;
    int wm = wid >> 1, wn = wid & 1;

    if (tid < 128) {
        int r = m0 + tid;
        toks[tid] = (r < cnt_e) ? p_tok[base + r] : 0;  // invalid -> token 0 (masked at write)
    }
    __syncthreads();

    // staging geometry: thread t covers LDS shorts [t*8, t*8+8) => row=t/4, col=(t&3)*8
    int srow = tid >> 2;          // 0..63 (call 0); +64 for call 1
    int scol = (tid & 3) * 8;
    const unsigned short* w13e = w13 + (size_t)e * (2 * I_DIM) * D_DIM;
    const unsigned short* aP0 = xb + (size_t)toks[srow] * D_DIM + scol;
    const unsigned short* aP1 = xb + (size_t)toks[srow + 64] * D_DIM + scol;
    const unsigned short* gP0 = w13e + (size_t)(n0 + srow) * D_DIM + scol;
    const unsigned short* gP1 = w13e + (size_t)(n0 + srow + 64) * D_DIM + scol;
    const unsigned short* uP0 = w13e + (size_t)(I_DIM + n0 + srow) * D_DIM + scol;
    const unsigned short* uP1 = w13e + (size_t)(I_DIM + n0 + srow + 64) * D_DIM + scol;
    int loOff = wid * 512;          // wave-uniform LDS short-offset, call 0
    int hiOff = 2048 + wid * 512;   // call 1 (rows 64..127)

    f32x4 accg[4][4], accu[4][4];
#pragma unroll
    for (int m = 0; m < 4; m++)
#pragma unroll
        for (int n = 0; n < 4; n++) {
            accg[m][n] = (f32x4){0.f, 0.f, 0.f, 0.f};
            accu[m][n] = (f32x4){0.f, 0.f, 0.f, 0.f};
        }

    int fr = lane & 15, fk = (lane >> 4) * 8;
    for (int k0 = 0; k0 < D_DIM; k0 += 32) {
        gll16(aP0, As + loOff);  gll16(aP1, As + hiOff);
        gll16(gP0, Bg + loOff);  gll16(gP1, Bg + hiOff);
        gll16(uP0, Bu + loOff);  gll16(uP1, Bu + hiOff);
        aP0 += 32; aP1 += 32; gP0 += 32; gP1 += 32; uP0 += 32; uP1 += 32;
        __syncthreads();

        bf16x8 a[4], bg[4], bu[4];
#pragma unroll
        for (int m = 0; m < 4; m++)
            a[m] = *(const bf16x8*)&As[(wm * 64 + m * 16 + fr) * 32 + fk];
#pragma unroll
        for (int n = 0; n < 4; n++) {
            bg[n] = *(const bf16x8*)&Bg[(wn * 64 + n * 16 + fr) * 32 + fk];
            bu[n] = *(const bf16x8*)&Bu[(wn * 64 + n * 16 + fr) * 32 + fk];
        }
#pragma unroll
        for (int m = 0; m < 4; m++)
#pragma unroll
            for (int n = 0; n < 4; n++) {
                accg[m][n] = __builtin_amdgcn_mfma_f32_16x16x32_bf16(a[m], bg[n], accg[m][n], 0, 0, 0);
                accu[m][n] = __builtin_amdgcn_mfma_f32_16x16x32_bf16(a[m], bu[n], accu[m][n], 0, 0, 0);
            }
        __syncthreads();
    }

    // epilogue: h = silu(g)*u, bf16
    int fq = lane >> 4;
#pragma unroll
    for (int m = 0; m < 4; m++) {
#pragma unroll
        for (int j = 0; j < 4; j++) {
            int rr = wm * 64 + m * 16 + fq * 4 + j;
            if (m0 + rr < cnt_e) {
                size_t hrow = (size_t)(base + m0 + rr) * I_DIM;
#pragma unroll
                for (int n = 0; n < 4; n++) {
                    float g = accg[m][n][j];
                    float u = accu[m][n][j];
                    float hh = (g / (1.f + __expf(-g))) * u;
                    h[hrow + n0 + wn * 64 + n * 16 + fr] = f2bf(hh);
                }
            }
        }
    }
}

// ---------------- GEMM2: partial[pos] = pw * (h[pos] @ w2^T)  (or atomic fallback) ----
template<bool USE_ATOMIC>
__global__ __launch_bounds__(256, 2) void gemm2_kernel(
    const unsigned short* __restrict__ h, const unsigned short* __restrict__ w2,
    const int* __restrict__ cnt, const int* __restrict__ off,
    const int* __restrict__ p_tok, const float* __restrict__ p_w,
    float* __restrict__ dst) {
    int e = blockIdx.z;
    int cnt_e = cnt[e];
    int m0 = blockIdx.y * 128;
    if (m0 >= cnt_e) return;
    int n0 = blockIdx.x * 128;
    int base = off[e];

    __shared__ unsigned short As[128 * 32];
    __shared__ unsigned short Bs[128 * 32];
    __shared__ int toks[128];
    __shared__ float pws[128];

    int tid = threadIdx.x;
    int lane = tid & 63, wid = tid >> 6;
    int wm = wid >> 1, wn = wid & 1;

    if (tid < 128) {
        int r = m0 + tid;
        toks[tid] = (r < cnt_e) ? p_tok[base + r] : 0;
        pws[tid]  = (r < cnt_e) ? p_w[base + r] : 0.f;
    }
    __syncthreads();

    int srow = tid >> 2;
    int scol = (tid & 3) * 8;
    // clamp gathered h rows to the buffer (garbage rows masked at epilogue)
    int ar0 = base + m0 + srow;      if (ar0 > NPAIR - 1) ar0 = NPAIR - 1;
    int ar1 = base + m0 + srow + 64; if (ar1 > NPAIR - 1) ar1 = NPAIR - 1;
    const unsigned short* aP0 = h + (size_t)ar0 * I_DIM + scol;
    const unsigned short* aP1 = h + (size_t)ar1 * I_DIM + scol;
    const unsigned short* w2e = w2 + (size_t)e * D_DIM * I_DIM;
    const unsigned short* bP0 = w2e + (size_t)(n0 + srow) * I_DIM + scol;
    const unsigned short* bP1 = w2e + (size_t)(n0 + srow + 64) * I_DIM + scol;
    int loOff = wid * 512;
    int hiOff = 2048 + wid * 512;

    f32x4 acc[4][4];
#pragma unroll
    for (int m = 0; m < 4; m++)
#pragma unroll
        for (int n = 0; n < 4; n++) acc[m][n] = (f32x4){0.f, 0.f, 0.f, 0.f};

    int fr = lane & 15, fk = (lane >> 4) * 8;
    for (int k0 = 0; k0 < I_DIM; k0 += 32) {
        gll16(aP0, As + loOff);  gll16(aP1, As + hiOff);
        gll16(bP0, Bs + loOff);  gll16(bP1, Bs + hiOff);
        aP0 += 32; aP1 += 32; bP0 += 32; bP1 += 32;
        __syncthreads();

        bf16x8 a[4], b[4];
#pragma unroll
        for (int m = 0; m < 4; m++)
            a[m] = *(const bf16x8*)&As[(wm * 64 + m * 16 + fr) * 32 + fk];
#pragma unroll
        for (int n = 0; n < 4; n++)
            b[n] = *(const bf16x8*)&Bs[(wn * 64 + n * 16 + fr) * 32 + fk];
#pragma unroll
        for (int m = 0; m < 4; m++)
#pragma unroll
            for (int n = 0; n < 4; n++)
                acc[m][n] = __builtin_amdgcn_mfma_f32_16x16x32_bf16(a[m], b[n], acc[m][n], 0, 0, 0);
        __syncthreads();
    }

    int fq = lane >> 4;
#pragma unroll
    for (int m = 0; m < 4; m++) {
#pragma unroll
        for (int j = 0; j < 4; j++) {
            int rr = wm * 64 + m * 16 + fq * 4 + j;
            if (m0 + rr < cnt_e) {
                float w = pws[rr];
#pragma unroll
                for (int n = 0; n < 4; n++) {
                    int col = n0 + wn * 64 + n * 16 + fr;
                    float v = acc[m][n][j] * w;
                    if (USE_ATOMIC) {
                        atomicAdd(&dst[(size_t)toks[rr] * D_DIM + col], v);
                    } else {
                        dst[(size_t)(base + m0 + rr) * D_DIM + col] = v;
                    }
                }
            }
        }
    }
}

// ---------------- combine: out[t] = sum_k partial[pair_of[t,k]] ----------------
__global__ __launch_bounds__(256) void combine_kernel(
    const float* __restrict__ part, const int* __restrict__ pair_of,
    float* __restrict__ out) {
    int t = blockIdx.x;
    int c = threadIdx.x * 4;
    int4 pr = *(const int4*)(pair_of + t * K_TOP);
    float4 s0 = *(const float4*)(part + (size_t)pr.x * D_DIM + c);
    float4 s1 = *(const float4*)(part + (size_t)pr.y * D_DIM + c);
    float4 s2 = *(const float4*)(part + (size_t)pr.z * D_DIM + c);
    float4 s3 = *(const float4*)(part + (size_t)pr.w * D_DIM + c);
    float4 r;
    r.x = (s0.x + s1.x) + (s2.x + s3.x);
    r.y = (s0.y + s1.y) + (s2.y + s3.y);
    r.z = (s0.z + s1.z) + (s2.z + s3.z);
    r.w = (s0.w + s1.w) + (s2.w + s3.w);
    *(float4*)(out + (size_t)t * D_DIM + c) = r;
}

// ---------------- launch ----------------
extern "C" void kernel_launch(void* const* d_in, const int* in_sizes, int n_in,
                              void* d_out, int out_size, void* d_ws, size_t ws_size,
                              hipStream_t stream) {
    const float* x      = (const float*)d_in[0];
    const float* logits = (const float*)d_in[1];
    const float* w13    = (const float*)d_in[2];
    const float* w2     = (const float*)d_in[3];
    float* out = (float*)d_out;
    char* ws = (char*)d_ws;

    unsigned short* xb   = (unsigned short*)(ws + WS_X);
    unsigned short* w13b = (unsigned short*)(ws + WS_W13);
    unsigned short* w2b  = (unsigned short*)(ws + WS_W2);
    unsigned short* hbuf = (unsigned short*)(ws + WS_H);
    int*   tk_id = (int*)(ws + WS_TKID);
    float* tk_w  = (float*)(ws + WS_TKW);
    int*   p_tok = (int*)(ws + WS_PTOK);
    float* p_w   = (float*)(ws + WS_PW);
    int* meta = (int*)(ws + WS_META);
    int* cnt = meta;
    int* cur = meta + 16;
    int* off = meta + 32;
    int*   pair_of = (int*)(ws + WS_PAIR);
    float* part    = (float*)(ws + WS_PART);

    bool full = (ws_size >= WS_NEED_FULL);

    hipMemsetAsync(meta, 0, 32 * sizeof(int), stream);
    if (!full) hipMemsetAsync(out, 0, (size_t)T_TOK * D_DIM * sizeof(float), stream);

    cvt_kernel<<<1024, 256, 0, stream>>>(x, xb, T_TOK * D_DIM);
    cvt_kernel<<<2048, 256, 0, stream>>>(w13, w13b, E_NUM * 2 * I_DIM * D_DIM);
    cvt_kernel<<<2048, 256, 0, stream>>>(w2, w2b, E_NUM * D_DIM * I_DIM);

    router_kernel<<<T_TOK / 256, 256, 0, stream>>>(logits, tk_id, tk_w, cnt);
    offsets_kernel<<<1, 64, 0, stream>>>(cnt, off, cur);
    scatter_kernel<<<T_TOK / 256, 256, 0, stream>>>(tk_id, tk_w, cur, p_tok, p_w, pair_of);

    dim3 g1(I_DIM / 128, 64, E_NUM);
    gemm1_kernel<<<g1, 256, 0, stream>>>(xb, w13b, cnt, off, p_tok, hbuf);

    dim3 g2(D_DIM / 128, 64, E_NUM);
    if (full) {
        gemm2_kernel<false><<<g2, 256, 0, stream>>>(hbuf, w2b, cnt, off, p_tok, p_w, part);
        combine_kernel<<<T_TOK, 256, 0, stream>>>(part, pair_of, out);
    } else {
        gemm2_kernel<true><<<g2, 256, 0, stream>>>(hbuf, w2b, cnt, off, p_tok, p_w, out);
    }
}